// Round 12
// baseline (759.685 us; speedup 1.0000x reference)
//
#include <hip/hip_runtime.h>

#define EMB   256
#define HID   128
#define RELD  64
#define NREL  10
#define TE    64

typedef __attribute__((ext_vector_type(8)))  short bf16x8;
typedef __attribute__((ext_vector_type(16))) float f32x16;

__device__ __forceinline__ float bf16_to_f32(unsigned short u) {
    union { unsigned int i; float f; } v;
    v.i = ((unsigned int)u) << 16;
    return v.f;
}

__device__ __forceinline__ unsigned short f32_to_bf16(float x) {
    union { unsigned int i; float f; } v;
    v.f = x;
    unsigned int b = v.i;
    unsigned int rounded = b + 0x7fffu + ((b >> 16) & 1u);   // round-nearest-even
    return (unsigned short)(rounded >> 16);
}

template <bool F32>
__device__ __forceinline__ float ldx(const void* p, size_t i) {
    if (F32) return ((const float*)p)[i];
    return bf16_to_f32(((const unsigned short*)p)[i]);
}

// In-kernel parallel dtype detect (validated rounds 7-11: fp32 inputs -> true).
__device__ __forceinline__ bool detect_f32(const void* nodeEmb) {
    const float* f = (const float*)nodeEmb;
    float x = f[(threadIdx.x & 63) * 997];
    bool sane = isfinite(x) && fabsf(x) < 1.0e6f;
    unsigned long long m = __ballot(sane);
    return __popcll(m) >= 48;
}

// ---------------------------------------------------------------------------
// Merged prep kernel:
//   blocks [0, convBlocks)            : fp32 node table -> bf16 copy (halves
//                                       the gather HBM traffic of the main
//                                       kernel; skipped if input already bf16)
//   blocks [convBlocks, +448)         : transpose 4 weights to bf16 [col][k]
//   block  convBlocks+448             : per-relation Q table (10x128 fp32)
// ---------------------------------------------------------------------------
template <bool F32>
__device__ void prep_body(int vb, const void* W_edge, const void* W_k,
                          const void* W_v, const void* W_o1, const void* rel_emb,
                          const void* W_q, const void* b_q,
                          unsigned short* WTe, unsigned short* WTk,
                          unsigned short* WTv, unsigned short* WTo1, float* Qtab)
{
    if (vb < 448) {
        int idx = vb * 256 + threadIdx.x;             // 0 .. 114687
        if (idx < 65536) {                            // W_edge: [512][128] -> [128][512]
            int col = idx >> 9, k = idx & 511;
            WTe[idx] = f32_to_bf16(ldx<F32>(W_edge, (size_t)k * HID + col));
        } else if (idx < 65536 + 16384) {
            int i = idx - 65536; int col = i >> 7, k = i & 127;
            WTk[i] = f32_to_bf16(ldx<F32>(W_k, (size_t)k * HID + col));
        } else if (idx < 65536 + 2 * 16384) {
            int i = idx - 65536 - 16384; int col = i >> 7, k = i & 127;
            WTv[i] = f32_to_bf16(ldx<F32>(W_v, (size_t)k * HID + col));
        } else {
            int i = idx - 65536 - 2 * 16384; int col = i >> 7, k = i & 127;
            WTo1[i] = f32_to_bf16(ldx<F32>(W_o1, (size_t)k * HID + col));
        }
    } else {
        const int t = threadIdx.x;
        const int c = t & (HID - 1);
        const int h = t >> 7;
        for (int r = h; r < NREL; r += 2) {
            float acc = 0.f;
            for (int d = 0; d < RELD; ++d)
                acc += ldx<F32>(rel_emb, r * RELD + d) * ldx<F32>(W_q, (size_t)d * HID + c);
            Qtab[r * HID + c] = acc + ldx<F32>(b_q, c);
        }
    }
}

__global__ void prep_kernel(const void* nodeEmb,
                            const void* W_edge, const void* W_k, const void* W_v,
                            const void* W_o1, const void* rel_emb, const void* W_q,
                            const void* b_q,
                            unsigned short* WTe, unsigned short* WTk,
                            unsigned short* WTv, unsigned short* WTo1, float* Qtab,
                            unsigned short* nodeBf16, int convBlocks,
                            unsigned long long nodeElems)
{
    bool f32 = detect_f32(nodeEmb);
    int b = blockIdx.x;
    if (b < convBlocks) {
        if (!f32) return;                             // bf16 input: no conversion
        unsigned long long i = (unsigned long long)b * 2048ull + threadIdx.x * 8;
        if (i + 8 <= nodeElems) {
            const float* src = (const float*)nodeEmb + i;
            float4 f0 = *(const float4*)src;
            float4 f1 = *(const float4*)(src + 4);
            union { unsigned short us[8]; uint4 v; } pk;
            pk.us[0] = f32_to_bf16(f0.x); pk.us[1] = f32_to_bf16(f0.y);
            pk.us[2] = f32_to_bf16(f0.z); pk.us[3] = f32_to_bf16(f0.w);
            pk.us[4] = f32_to_bf16(f1.x); pk.us[5] = f32_to_bf16(f1.y);
            pk.us[6] = f32_to_bf16(f1.z); pk.us[7] = f32_to_bf16(f1.w);
            *(uint4*)(nodeBf16 + i) = pk.v;
        }
        return;
    }
    b -= convBlocks;
    if (f32) prep_body<true >(b, W_edge, W_k, W_v, W_o1, rel_emb, W_q, b_q,
                              WTe, WTk, WTv, WTo1, Qtab);
    else     prep_body<false>(b, W_edge, W_k, W_v, W_o1, rel_emb, W_q, b_q,
                              WTe, WTk, WTv, WTo1, Qtab);
}

// Shared memory: single allocation in the wrapper (round-7 lesson).
// 36.6 KB -> 4 blocks/CU.
struct __align__(16) Smem {
    unsigned short sHid[TE][136];    // 17408 B
    union {
        unsigned short sA[TE][40];   // GEMM1 gathered-feature k-chunk
        float sQf[NREL * HID];       // Q table (score phase) -- disjoint live ranges
    } u;                             // 5120 B
    unsigned short sB[4096];         // 8192 B: frag-major B chunk, unit u = 16B,
                                     //   u = ((col>>5)*4 + kg)*32 + (col&31)
                                     //   -> MFMA B-reads are lane-linear (0-conflict)
    float sBias[5 * HID];            // 2560 B: b_edge|b_k|b_v|b_o1|W_o2
    float sSc[TE][4], sAttn[TE][4];  // 2048 B
    float sPart[TE][2];              // 512 B
    int   sSrc[TE], sTgt[TE], sRel[TE];  // 768 B
};

// One K=128 GEMM (4 chunks), 32x32x16 MFMA, A resident in sHid.
// pb holds chunk kc's B in registers on entry (software pipeline); on exit pb
// holds chunk 0 of WTnext (if non-null).
__device__ __forceinline__ void gemm128(Smem& sm, const unsigned short* WT,
                                        const unsigned short* WTnext,
                                        f32x16* acc, int t, int rt, int cg2,
                                        int c, int h5, int l, uint4* pb)
{
    for (int kc = 0; kc < 4; ++kc) {
        __syncthreads();                      // prior chunk's LDS fully consumed
        #pragma unroll
        for (int j = 0; j < 2; ++j) {         // store chunk kc from regs
            int g = t + j * 256, col = g & 127, kg = g >> 7;
            int uu = ((col >> 5) * 4 + kg) * 32 + (col & 31);
            *(uint4*)&sm.sB[uu * 8] = pb[j];
        }
        __syncthreads();
        const unsigned short* Wn = (kc < 3) ? WT : WTnext;   // prefetch next
        int kcn = (kc < 3) ? kc + 1 : 0;
        if (Wn) {
            #pragma unroll
            for (int j = 0; j < 2; ++j) {
                int g = t + j * 256, col = g & 127, kg = g >> 7;
                pb[j] = *(const uint4*)(Wn + (size_t)col * HID + kcn * 32 + kg * 8);
            }
        }
        #pragma unroll
        for (int s = 0; s < 2; ++s) {
            bf16x8 a = *(const bf16x8*)&sm.sHid[32 * rt + c][kc * 32 + s * 16 + h5 * 8];
            #pragma unroll
            for (int ct = 0; ct < 2; ++ct) {
                bf16x8 b = *(const bf16x8*)&sm.sB[((cg2 * 2 + ct) * 128 + s * 64 + l) * 8];
                acc[ct] = __builtin_amdgcn_mfma_f32_32x32x16_bf16(a, b, acc[ct], 0, 0, 0);
            }
        }
    }
}

// ---------------------------------------------------------------------------
// Fused pipeline, 32x32x16 MFMA + register-prefetch software pipeline.
// Block = 64 edges, 256 threads = 4 waves. Wave w: rt=w&1 rows, cg2=w>>1 cols.
// F32: weights/biases fp32; GBF16: gather source is bf16 (pre-converted table
// or native bf16 input).
// ---------------------------------------------------------------------------
template <bool F32, bool GBF16>
__device__ void fused_body(
    Smem& sm,
    const void* gsrc, const int* edgeIdx, const int* relType,
    const unsigned short* WTe, const unsigned short* WTk,
    const unsigned short* WTv, const unsigned short* WTo1,
    const void* b_edge, const void* b_k, const void* b_v,
    const void* b_o1, const void* W_o2, const void* b_o2,
    const float* Qtab, void* outp, int E)
{
    const int t   = threadIdx.x;
    const int l   = t & 63;
    const int w   = t >> 6;
    const int c   = l & 31;
    const int h5  = l >> 5;
    const int rt  = w & 1;
    const int cg2 = w >> 1;
    const int bs  = blockIdx.x * TE;

    // ---- preamble ----
    if (t < TE) {
        int e = bs + t;
        if (e >= E) e = E - 1;
        if (e < 0)  e = 0;
        sm.sSrc[t] = edgeIdx[e];
        sm.sTgt[t] = edgeIdx[E + e];
        int r = relType[e];
        if (r < 0) r = 0;
        if (r >= NREL) r = NREL - 1;
        sm.sRel[t] = r;
    }
    for (int i = t; i < 5 * HID; i += 256) {
        int which = i >> 7, j = i & (HID - 1);
        float v = (which == 0) ? ldx<F32>(b_edge, j)
                : (which == 1) ? ldx<F32>(b_k, j)
                : (which == 2) ? ldx<F32>(b_v, j)
                : (which == 3) ? ldx<F32>(b_o1, j)
                               : ldx<F32>(W_o2, j);
        sm.sBias[i] = v;
    }
    __syncthreads();

    const int edge_s = t >> 2;    // staging: edge 0..63
    const int grp    = t & 3;     // staging: 8-elem group 0..3

    uint4  paU;                   // gather prefetch (bf16 path)
    float4 paF0, paF1;            //                 (fp32 path)
    uint4  pb[2];                 // B prefetch

    // ---- prefetch chunk 0 of GEMM1 ----
    {
        int node = sm.sSrc[edge_s];
        int col0 = grp * 8;
        if (GBF16) {
            paU = *(const uint4*)((const unsigned short*)gsrc + (size_t)node * EMB + col0);
        } else {
            const float* p = (const float*)gsrc + (size_t)node * EMB + col0;
            paF0 = *(const float4*)p; paF1 = *(const float4*)(p + 4);
        }
        #pragma unroll
        for (int j = 0; j < 2; ++j) {
            int g = t + j * 256, col = g & 127, kg = g >> 7;
            pb[j] = *(const uint4*)(WTe + (size_t)col * 512 + kg * 8);
        }
    }

    // ---- GEMM1: hid = relu([src|tgt] @ W_edge + b_edge), K=512 in 16 chunks ----
    f32x16 acc[2];
    acc[0] = (f32x16)(0.0f); acc[1] = (f32x16)(0.0f);
    for (int kc = 0; kc < 16; ++kc) {
        __syncthreads();
        // store A chunk from regs
        if (GBF16) {
            *(uint4*)&sm.u.sA[edge_s][grp * 8] = paU;
        } else {
            union { unsigned short us[8]; uint4 v; } pk;
            pk.us[0] = f32_to_bf16(paF0.x); pk.us[1] = f32_to_bf16(paF0.y);
            pk.us[2] = f32_to_bf16(paF0.z); pk.us[3] = f32_to_bf16(paF0.w);
            pk.us[4] = f32_to_bf16(paF1.x); pk.us[5] = f32_to_bf16(paF1.y);
            pk.us[6] = f32_to_bf16(paF1.z); pk.us[7] = f32_to_bf16(paF1.w);
            *(uint4*)&sm.u.sA[edge_s][grp * 8] = pk.v;
        }
        // store B chunk from regs (frag-major, lane-linear)
        #pragma unroll
        for (int j = 0; j < 2; ++j) {
            int g = t + j * 256, col = g & 127, kg = g >> 7;
            int uu = ((col >> 5) * 4 + kg) * 32 + (col & 31);
            *(uint4*)&sm.sB[uu * 8] = pb[j];
        }
        __syncthreads();
        // prefetch next chunk (overlaps the MFMA below + next barriers)
        if (kc < 15) {
            int kn = kc + 1;
            int node = (kn < 8) ? sm.sSrc[edge_s] : sm.sTgt[edge_s];
            int col0 = (kn & 7) * 32 + grp * 8;
            if (GBF16) {
                paU = *(const uint4*)((const unsigned short*)gsrc + (size_t)node * EMB + col0);
            } else {
                const float* p = (const float*)gsrc + (size_t)node * EMB + col0;
                paF0 = *(const float4*)p; paF1 = *(const float4*)(p + 4);
            }
            #pragma unroll
            for (int j = 0; j < 2; ++j) {
                int g = t + j * 256, col = g & 127, kg = g >> 7;
                pb[j] = *(const uint4*)(WTe + (size_t)col * 512 + kn * 32 + kg * 8);
            }
        } else {
            #pragma unroll
            for (int j = 0; j < 2; ++j) {     // cross-GEMM: WTk chunk 0
                int g = t + j * 256, col = g & 127, kg = g >> 7;
                pb[j] = *(const uint4*)(WTk + (size_t)col * HID + kg * 8);
            }
        }
        #pragma unroll
        for (int s = 0; s < 2; ++s) {
            bf16x8 a = *(const bf16x8*)&sm.u.sA[32 * rt + c][s * 16 + h5 * 8];
            #pragma unroll
            for (int ct = 0; ct < 2; ++ct) {
                bf16x8 b = *(const bf16x8*)&sm.sB[((cg2 * 2 + ct) * 128 + s * 64 + l) * 8];
                acc[ct] = __builtin_amdgcn_mfma_f32_32x32x16_bf16(a, b, acc[ct], 0, 0, 0);
            }
        }
    }
    {   // epilogue: + b_edge, relu -> sHid (bf16)
        #pragma unroll
        for (int ct = 0; ct < 2; ++ct) {
            int col = 64 * cg2 + 32 * ct + c;
            float bb = sm.sBias[col];
            #pragma unroll
            for (int r = 0; r < 16; ++r) {
                int erow = 32 * rt + (r & 3) + 8 * (r >> 2) + 4 * h5;
                sm.sHid[erow][col] = f32_to_bf16(fmaxf(acc[ct][r] + bb, 0.f));
            }
        }
    }
    __syncthreads();   // all GEMM1 sA reads done -> union becomes sQf
    for (int i = t; i < NREL * HID; i += 256)
        sm.u.sQf[i] = Qtab[i];
    // (visible after gemm128's internal barriers)

    // ---- K GEMM (pb pre-loaded with WTk chunk 0; exits with WTv chunk 0) ----
    f32x16 kacc[2];
    kacc[0] = (f32x16)(0.0f); kacc[1] = (f32x16)(0.0f);
    gemm128(sm, WTk, WTv, kacc, t, rt, cg2, c, h5, l, pb);

    // ---- scores[e][h] = sum_col Q[rel][col]*(K+bk)[e][col] / sqrt(32) ----
    {
        float ps[2][16];
        #pragma unroll
        for (int ct = 0; ct < 2; ++ct) {
            int col = 64 * cg2 + 32 * ct + c;
            float bk = sm.sBias[HID + col];
            #pragma unroll
            for (int r = 0; r < 16; ++r) {
                int erow = 32 * rt + (r & 3) + 8 * (r >> 2) + 4 * h5;
                ps[ct][r] = (kacc[ct][r] + bk) * sm.u.sQf[sm.sRel[erow] * HID + col];
            }
        }
        #pragma unroll
        for (int m = 1; m < 32; m <<= 1)
            #pragma unroll
            for (int ct = 0; ct < 2; ++ct)
                #pragma unroll
                for (int r = 0; r < 16; ++r)
                    ps[ct][r] += __shfl_xor(ps[ct][r], m, 64);
        if (c == 0) {
            const float inv = 0.17677669529663687f;   // 1/sqrt(32)
            #pragma unroll
            for (int ct = 0; ct < 2; ++ct) {
                int head = 2 * cg2 + ct;
                #pragma unroll
                for (int r = 0; r < 16; ++r) {
                    int erow = 32 * rt + (r & 3) + 8 * (r >> 2) + 4 * h5;
                    sm.sSc[erow][head] = ps[ct][r] * inv;
                }
            }
        }
    }
    __syncthreads();
    if (t < TE) {   // softmax over 4 heads
        float s0 = sm.sSc[t][0], s1 = sm.sSc[t][1];
        float s2 = sm.sSc[t][2], s3 = sm.sSc[t][3];
        float m = fmaxf(fmaxf(s0, s1), fmaxf(s2, s3));
        float e0 = expf(s0 - m), e1 = expf(s1 - m);
        float e2 = expf(s2 - m), e3 = expf(s3 - m);
        float den = e0 + e1 + e2 + e3;
        sm.sAttn[t][0] = e0 / den; sm.sAttn[t][1] = e1 / den;
        sm.sAttn[t][2] = e2 / den; sm.sAttn[t][3] = e3 / den;
    }
    __syncthreads();

    // ---- V GEMM (pb holds WTv chunk 0; exits with WTo1 chunk 0) ----
    f32x16 vacc[2];
    vacc[0] = (f32x16)(0.0f); vacc[1] = (f32x16)(0.0f);
    gemm128(sm, WTv, WTo1, vacc, t, rt, cg2, c, h5, l, pb);
    {   // out[e][col] = attn[e][h]*(V+bv) + hid[e][col], same-lane in-place
        #pragma unroll
        for (int ct = 0; ct < 2; ++ct) {
            int col  = 64 * cg2 + 32 * ct + c;
            int head = 2 * cg2 + ct;
            float bv = sm.sBias[2 * HID + col];
            #pragma unroll
            for (int r = 0; r < 16; ++r) {
                int erow = 32 * rt + (r & 3) + 8 * (r >> 2) + 4 * h5;
                float at = sm.sAttn[erow][head];
                float hv = bf16_to_f32(sm.sHid[erow][col]);
                sm.sHid[erow][col] = f32_to_bf16(at * (vacc[ct][r] + bv) + hv);
            }
        }
    }
    // (first barrier inside the next gemm128 covers the in-place hazard)

    // ---- GEMM3 + final dot with W_o2 ----
    f32x16 oacc[2];
    oacc[0] = (f32x16)(0.0f); oacc[1] = (f32x16)(0.0f);
    gemm128(sm, WTo1, nullptr, oacc, t, rt, cg2, c, h5, l, pb);
    {
        float pr[16];
        #pragma unroll
        for (int r = 0; r < 16; ++r) pr[r] = 0.f;
        #pragma unroll
        for (int ct = 0; ct < 2; ++ct) {
            int col = 64 * cg2 + 32 * ct + c;
            float bo = sm.sBias[3 * HID + col];
            float wo = sm.sBias[4 * HID + col];
            #pragma unroll
            for (int r = 0; r < 16; ++r)
                pr[r] += fmaxf(oacc[ct][r] + bo, 0.f) * wo;
        }
        #pragma unroll
        for (int m = 1; m < 32; m <<= 1)
            #pragma unroll
            for (int r = 0; r < 16; ++r)
                pr[r] += __shfl_xor(pr[r], m, 64);
        if (c == 0) {
            #pragma unroll
            for (int r = 0; r < 16; ++r) {
                int erow = 32 * rt + (r & 3) + 8 * (r >> 2) + 4 * h5;
                sm.sPart[erow][cg2] = pr[r];
            }
        }
    }
    __syncthreads();
    if (t < TE) {
        int ge = bs + t;
        if (ge < E) {
            float val = sm.sPart[t][0] + sm.sPart[t][1] + ldx<F32>(b_o2, 0);
            // F32 path writes fp32 (round-10 lesson: output buffer is fp32).
            if (F32) ((float*)outp)[ge] = val;
            else     ((unsigned short*)outp)[ge] = f32_to_bf16(val);
        }
    }
}

__global__ __launch_bounds__(256, 4) void RelationAttentionMLPHead_10539849744626_kernel(
    const void* nodeEmb, const unsigned short* nodeBf16, int useConv,
    const int* edgeIdx, const int* relType,
    const unsigned short* WTe, const unsigned short* WTk,
    const unsigned short* WTv, const unsigned short* WTo1,
    const void* b_edge, const void* b_k, const void* b_v,
    const void* b_o1, const void* W_o2, const void* b_o2,
    const float* Qtab, void* outp, int E)
{
    __shared__ Smem sm;     // single allocation shared by all instantiations
    if (detect_f32(nodeEmb)) {
        if (useConv)
            fused_body<true, true >(sm, nodeBf16, edgeIdx, relType, WTe, WTk, WTv, WTo1,
                                    b_edge, b_k, b_v, b_o1, W_o2, b_o2, Qtab, outp, E);
        else
            fused_body<true, false>(sm, nodeEmb, edgeIdx, relType, WTe, WTk, WTv, WTo1,
                                    b_edge, b_k, b_v, b_o1, W_o2, b_o2, Qtab, outp, E);
    } else {
        fused_body<false, true>(sm, nodeEmb, edgeIdx, relType, WTe, WTk, WTv, WTo1,
                                b_edge, b_k, b_v, b_o1, W_o2, b_o2, Qtab, outp, E);
    }
}

extern "C" void kernel_launch(void* const* d_in, const int* in_sizes, int n_in,
                              void* d_out, int out_size, void* d_ws, size_t ws_size,
                              hipStream_t stream) {
    (void)n_in;

    const void* nodeEmb = d_in[0];
    const int*  edgeIdx = (const int*)d_in[1];
    const int*  relType = (const int*)d_in[2];
    const void* rel_emb = d_in[3];
    const void* W_edge  = d_in[4];
    const void* b_edge  = d_in[5];
    const void* W_q     = d_in[6];
    const void* b_q     = d_in[7];
    const void* W_k     = d_in[8];
    const void* b_k     = d_in[9];
    const void* W_v     = d_in[10];
    const void* b_v     = d_in[11];
    const void* W_o1    = d_in[12];
    const void* b_o1    = d_in[13];
    const void* W_o2    = d_in[14];
    const void* b_o2    = d_in[15];

    int E = out_size;
    if (E <= 0) E = in_sizes ? in_sizes[2] : 0;
    if (E <= 0) E = 500000;

    unsigned long long nodeElems =
        (in_sizes && in_sizes[0] > 0) ? (unsigned long long)in_sizes[0] : 25600000ull;

    // d_ws layout (recomputed every launch; graph-safe)
    char* ws = (char*)d_ws;
    float*          Qtab     = (float*)ws;                      // 5120 B
    unsigned short* WTe      = (unsigned short*)(ws + 8192);    // 131072 B
    unsigned short* WTk      = (unsigned short*)(ws + 139264);  // 32768 B
    unsigned short* WTv      = (unsigned short*)(ws + 172032);  // 32768 B
    unsigned short* WTo1     = (unsigned short*)(ws + 204800);  // 32768 B
    unsigned short* nodeBf16 = (unsigned short*)(ws + 237568);  // nodeElems*2 B

    size_t need = 237568ull + nodeElems * 2ull;
    int useConv = (ws_size >= need) ? 1 : 0;
    int convBlocks = useConv ? (int)((nodeElems + 2047ull) / 2048ull) : 0;

    prep_kernel<<<convBlocks + 449, 256, 0, stream>>>(
        nodeEmb, W_edge, W_k, W_v, W_o1, rel_emb, W_q, b_q,
        WTe, WTk, WTv, WTo1, Qtab, nodeBf16, convBlocks, nodeElems);

    int grid = (E + TE - 1) / TE;
    if (grid < 1) grid = 1;

    RelationAttentionMLPHead_10539849744626_kernel<<<grid, 256, 0, stream>>>(
        nodeEmb, nodeBf16, useConv, edgeIdx, relType, WTe, WTk, WTv, WTo1,
        b_edge, b_k, b_v, b_o1, W_o2, b_o2, Qtab, d_out, E);
}

// Round 13
// 443.782 us; speedup vs baseline: 1.7118x; 1.7118x over previous
//
#include <hip/hip_runtime.h>

#define EMB   256
#define HID   128
#define RELD  64
#define NREL  10
#define TE    64

typedef __attribute__((ext_vector_type(8)))  short bf16x8;
typedef __attribute__((ext_vector_type(16))) float f32x16;

__device__ __forceinline__ float bf16_to_f32(unsigned short u) {
    union { unsigned int i; float f; } v;
    v.i = ((unsigned int)u) << 16;
    return v.f;
}

__device__ __forceinline__ unsigned short f32_to_bf16(float x) {
    union { unsigned int i; float f; } v;
    v.f = x;
    unsigned int b = v.i;
    unsigned int rounded = b + 0x7fffu + ((b >> 16) & 1u);   // round-nearest-even
    return (unsigned short)(rounded >> 16);
}

template <bool F32>
__device__ __forceinline__ float ldx(const void* p, size_t i) {
    if (F32) return ((const float*)p)[i];
    return bf16_to_f32(((const unsigned short*)p)[i]);
}

// In-kernel parallel dtype detect (validated rounds 7-12: fp32 inputs -> true).
__device__ __forceinline__ bool detect_f32(const void* nodeEmb) {
    const float* f = (const float*)nodeEmb;
    float x = f[(threadIdx.x & 63) * 997];
    bool sane = isfinite(x) && fabsf(x) < 1.0e6f;
    unsigned long long m = __ballot(sane);
    return __popcll(m) >= 48;
}

// ---------------------------------------------------------------------------
// Merged prep kernel:
//   blocks [0, convBlocks)    : fp32 node table -> bf16 copy (halves gather
//                               HBM traffic; skipped when input already bf16)
//   blocks [convBlocks, +448) : weights -> bf16 in STAGING ORDER: per K-chunk
//                               (32 k), 512 16-B units, unit g holds
//                               W[kc*32 + (g>>7)*8 .. +7][g&127]. The main
//                               kernel's staging load is then thread-linear
//                               (1 KB contiguous per wave -> coalesced).
//   block  convBlocks+448     : per-relation Q table (10x128 fp32)
// ---------------------------------------------------------------------------
template <bool F32>
__device__ void prep_body(int vb, const void* W_edge, const void* W_k,
                          const void* W_v, const void* W_o1, const void* rel_emb,
                          const void* W_q, const void* b_q,
                          unsigned short* WTe, unsigned short* WTk,
                          unsigned short* WTv, unsigned short* WTo1, float* Qtab)
{
    if (vb < 448) {
        int idx = vb * 256 + threadIdx.x;             // 0 .. 114687
        if (idx < 65536) {                            // W_edge: 16 chunks x 4096
            int kc = idx >> 12, e = idx & 4095;
            int g = e >> 3, j = e & 7;
            int col = g & 127, kg = g >> 7;
            int k = kc * 32 + kg * 8 + j;
            WTe[idx] = f32_to_bf16(ldx<F32>(W_edge, (size_t)k * HID + col));
        } else if (idx < 65536 + 16384) {             // W_k: 4 chunks x 4096
            int i = idx - 65536;
            int kc = i >> 12, e = i & 4095;
            int g = e >> 3, j = e & 7;
            int col = g & 127, kg = (g >> 7) & 3;
            int k = kc * 32 + kg * 8 + j;
            WTk[i] = f32_to_bf16(ldx<F32>(W_k, (size_t)k * HID + col));
        } else if (idx < 65536 + 2 * 16384) {
            int i = idx - 65536 - 16384;
            int kc = i >> 12, e = i & 4095;
            int g = e >> 3, j = e & 7;
            int col = g & 127, kg = (g >> 7) & 3;
            int k = kc * 32 + kg * 8 + j;
            WTv[i] = f32_to_bf16(ldx<F32>(W_v, (size_t)k * HID + col));
        } else {
            int i = idx - 65536 - 2 * 16384;
            int kc = i >> 12, e = i & 4095;
            int g = e >> 3, j = e & 7;
            int col = g & 127, kg = (g >> 7) & 3;
            int k = kc * 32 + kg * 8 + j;
            WTo1[i] = f32_to_bf16(ldx<F32>(W_o1, (size_t)k * HID + col));
        }
    } else {
        const int t = threadIdx.x;
        const int c = t & (HID - 1);
        const int h = t >> 7;
        for (int r = h; r < NREL; r += 2) {
            float acc = 0.f;
            for (int d = 0; d < RELD; ++d)
                acc += ldx<F32>(rel_emb, r * RELD + d) * ldx<F32>(W_q, (size_t)d * HID + c);
            Qtab[r * HID + c] = acc + ldx<F32>(b_q, c);
        }
    }
}

__global__ void prep_kernel(const void* nodeEmb,
                            const void* W_edge, const void* W_k, const void* W_v,
                            const void* W_o1, const void* rel_emb, const void* W_q,
                            const void* b_q,
                            unsigned short* WTe, unsigned short* WTk,
                            unsigned short* WTv, unsigned short* WTo1, float* Qtab,
                            unsigned short* nodeBf16, int convBlocks,
                            unsigned long long nodeElems)
{
    bool f32 = detect_f32(nodeEmb);
    int b = blockIdx.x;
    if (b < convBlocks) {
        if (!f32) return;                             // bf16 input: no conversion
        unsigned long long i = (unsigned long long)b * 2048ull + threadIdx.x * 8;
        if (i + 8 <= nodeElems) {
            const float* src = (const float*)nodeEmb + i;
            float4 f0 = *(const float4*)src;
            float4 f1 = *(const float4*)(src + 4);
            union { unsigned short us[8]; uint4 v; } pk;
            pk.us[0] = f32_to_bf16(f0.x); pk.us[1] = f32_to_bf16(f0.y);
            pk.us[2] = f32_to_bf16(f0.z); pk.us[3] = f32_to_bf16(f0.w);
            pk.us[4] = f32_to_bf16(f1.x); pk.us[5] = f32_to_bf16(f1.y);
            pk.us[6] = f32_to_bf16(f1.z); pk.us[7] = f32_to_bf16(f1.w);
            *(uint4*)(nodeBf16 + i) = pk.v;
        }
        return;
    }
    b -= convBlocks;
    if (f32) prep_body<true >(b, W_edge, W_k, W_v, W_o1, rel_emb, W_q, b_q,
                              WTe, WTk, WTv, WTo1, Qtab);
    else     prep_body<false>(b, W_edge, W_k, W_v, W_o1, rel_emb, W_q, b_q,
                              WTe, WTk, WTv, WTo1, Qtab);
}

// Shared memory: single allocation in the wrapper (round-7 lesson). 36.6 KB.
struct __align__(16) Smem {
    unsigned short sHid[TE][136];    // 17408 B
    union {
        unsigned short sA[TE][40];   // GEMM1 gathered-feature k-chunk
        float sQf[NREL * HID];       // Q table (score phase) -- disjoint live ranges
    } u;                             // 5120 B
    unsigned short sB[4096];         // 8192 B: B chunk in staging order (unit g:
                                     //   col = g&127, kg = g>>7) -- thread-linear
                                     //   stores AND lane-linear MFMA reads
    float sBias[5 * HID];            // 2560 B: b_edge|b_k|b_v|b_o1|W_o2
    float sSc[TE][4], sAttn[TE][4];  // 2048 B
    float sPart[TE][2];              // 512 B
    int   sSrc[TE], sTgt[TE], sRel[TE];  // 768 B
};

// One K=128 GEMM (4 chunks), 32x32x16 MFMA, A resident in sHid.
// No cross-barrier register state (round-12 lesson: that path spilled to
// scratch, 184 MB/dispatch of HBM writes).
__device__ __forceinline__ void gemm128(Smem& sm, const unsigned short* WT,
                                        f32x16* acc, int t, int rt, int cg2,
                                        int c, int h5)
{
    for (int kc = 0; kc < 4; ++kc) {
        const unsigned short* base = WT + kc * 4096;
        __syncthreads();                      // prior chunk's LDS fully consumed
        *(uint4*)&sm.sB[(size_t)t * 8]         = *(const uint4*)(base + (size_t)t * 8);
        *(uint4*)&sm.sB[(size_t)(t + 256) * 8] = *(const uint4*)(base + (size_t)(t + 256) * 8);
        __syncthreads();
        #pragma unroll
        for (int s = 0; s < 2; ++s) {
            bf16x8 a = *(const bf16x8*)&sm.sHid[32 * rt + c][kc * 32 + s * 16 + h5 * 8];
            #pragma unroll
            for (int ct = 0; ct < 2; ++ct) {
                bf16x8 b = *(const bf16x8*)
                    &sm.sB[((s * 2 + h5) * 128 + 64 * cg2 + 32 * ct + c) * 8];
                acc[ct] = __builtin_amdgcn_mfma_f32_32x32x16_bf16(a, b, acc[ct], 0, 0, 0);
            }
        }
    }
}

// ---------------------------------------------------------------------------
// Fused pipeline, 32x32x16 MFMA. Block = 64 edges, 256 threads = 4 waves.
// Wave w: rt=w&1 (rows 32rt..+31), cg2=w>>1 (cols 64cg2..+63).
//   A-frag: lane l -> A[m = l&31][k = (l>>5)*8 + j]
//   B-frag: lane l -> B[k = (l>>5)*8 + j][n = l&31]
//   C/D:    lane l, reg r -> row = (r&3) + 8*(r>>2) + 4*(l>>5), col = l&31
// ---------------------------------------------------------------------------
template <bool F32, bool GBF16>
__device__ void fused_body(
    Smem& sm,
    const void* gsrc, const int* edgeIdx, const int* relType,
    const unsigned short* WTe, const unsigned short* WTk,
    const unsigned short* WTv, const unsigned short* WTo1,
    const void* b_edge, const void* b_k, const void* b_v,
    const void* b_o1, const void* W_o2, const void* b_o2,
    const float* Qtab, void* outp, int E)
{
    const int t   = threadIdx.x;
    const int l   = t & 63;
    const int w   = t >> 6;
    const int c   = l & 31;
    const int h5  = l >> 5;
    const int rt  = w & 1;
    const int cg2 = w >> 1;
    const int bs  = blockIdx.x * TE;

    // ---- preamble ----
    if (t < TE) {
        int e = bs + t;
        if (e >= E) e = E - 1;
        if (e < 0)  e = 0;
        sm.sSrc[t] = edgeIdx[e];
        sm.sTgt[t] = edgeIdx[E + e];
        int r = relType[e];
        if (r < 0) r = 0;
        if (r >= NREL) r = NREL - 1;
        sm.sRel[t] = r;
    }
    for (int i = t; i < 5 * HID; i += 256) {
        int which = i >> 7, j = i & (HID - 1);
        float v = (which == 0) ? ldx<F32>(b_edge, j)
                : (which == 1) ? ldx<F32>(b_k, j)
                : (which == 2) ? ldx<F32>(b_v, j)
                : (which == 3) ? ldx<F32>(b_o1, j)
                               : ldx<F32>(W_o2, j);
        sm.sBias[i] = v;
    }
    __syncthreads();

    const int edge_s = t >> 2;    // staging: edge 0..63
    const int grp    = t & 3;     // staging: 8-elem group 0..3

    // ---- GEMM1: hid = relu([src|tgt] @ W_edge + b_edge), K=512 in 16 chunks ----
    f32x16 acc[2];
    acc[0] = (f32x16)(0.0f); acc[1] = (f32x16)(0.0f);
    for (int kc = 0; kc < 16; ++kc) {
        __syncthreads();
        {   // stage A chunk: 64 edges x 32 k bf16
            int node = (kc < 8) ? sm.sSrc[edge_s] : sm.sTgt[edge_s];
            int col0 = (kc & 7) * 32 + grp * 8;
            if (GBF16) {
                *(uint4*)&sm.u.sA[edge_s][grp * 8] =
                    *(const uint4*)((const unsigned short*)gsrc +
                                    (size_t)node * EMB + col0);
            } else {
                const float* p = (const float*)gsrc + (size_t)node * EMB + col0;
                float4 f0 = *(const float4*)p;
                float4 f1 = *(const float4*)(p + 4);
                union { unsigned short us[8]; uint4 v; } pk;
                pk.us[0] = f32_to_bf16(f0.x); pk.us[1] = f32_to_bf16(f0.y);
                pk.us[2] = f32_to_bf16(f0.z); pk.us[3] = f32_to_bf16(f0.w);
                pk.us[4] = f32_to_bf16(f1.x); pk.us[5] = f32_to_bf16(f1.y);
                pk.us[6] = f32_to_bf16(f1.z); pk.us[7] = f32_to_bf16(f1.w);
                *(uint4*)&sm.u.sA[edge_s][grp * 8] = pk.v;
            }
        }
        {   // stage B chunk: thread-linear (coalesced 1 KB/wave)
            const unsigned short* base = WTe + kc * 4096;
            *(uint4*)&sm.sB[(size_t)t * 8]         = *(const uint4*)(base + (size_t)t * 8);
            *(uint4*)&sm.sB[(size_t)(t + 256) * 8] = *(const uint4*)(base + (size_t)(t + 256) * 8);
        }
        __syncthreads();
        #pragma unroll
        for (int s = 0; s < 2; ++s) {
            bf16x8 a = *(const bf16x8*)&sm.u.sA[32 * rt + c][s * 16 + h5 * 8];
            #pragma unroll
            for (int ct = 0; ct < 2; ++ct) {
                bf16x8 b = *(const bf16x8*)
                    &sm.sB[((s * 2 + h5) * 128 + 64 * cg2 + 32 * ct + c) * 8];
                acc[ct] = __builtin_amdgcn_mfma_f32_32x32x16_bf16(a, b, acc[ct], 0, 0, 0);
            }
        }
    }
    {   // epilogue: + b_edge, relu -> sHid (bf16)
        #pragma unroll
        for (int ct = 0; ct < 2; ++ct) {
            int col = 64 * cg2 + 32 * ct + c;
            float bb = sm.sBias[col];
            #pragma unroll
            for (int r = 0; r < 16; ++r) {
                int erow = 32 * rt + (r & 3) + 8 * (r >> 2) + 4 * h5;
                sm.sHid[erow][col] = f32_to_bf16(fmaxf(acc[ct][r] + bb, 0.f));
            }
        }
    }
    __syncthreads();   // all GEMM1 sA reads done -> union becomes sQf
    for (int i = t; i < NREL * HID; i += 256)
        sm.u.sQf[i] = Qtab[i];
    // (visible after gemm128's internal barriers)

    // ---- K GEMM ----
    f32x16 kacc[2];
    kacc[0] = (f32x16)(0.0f); kacc[1] = (f32x16)(0.0f);
    gemm128(sm, WTk, kacc, t, rt, cg2, c, h5);

    // ---- scores[e][h] = sum_col Q[rel][col]*(K+bk)[e][col] / sqrt(32) ----
    {
        float ps[2][16];
        #pragma unroll
        for (int ct = 0; ct < 2; ++ct) {
            int col = 64 * cg2 + 32 * ct + c;
            float bk = sm.sBias[HID + col];
            #pragma unroll
            for (int r = 0; r < 16; ++r) {
                int erow = 32 * rt + (r & 3) + 8 * (r >> 2) + 4 * h5;
                ps[ct][r] = (kacc[ct][r] + bk) * sm.u.sQf[sm.sRel[erow] * HID + col];
            }
        }
        #pragma unroll
        for (int m = 1; m < 32; m <<= 1)
            #pragma unroll
            for (int ct = 0; ct < 2; ++ct)
                #pragma unroll
                for (int r = 0; r < 16; ++r)
                    ps[ct][r] += __shfl_xor(ps[ct][r], m, 64);
        if (c == 0) {
            const float inv = 0.17677669529663687f;   // 1/sqrt(32)
            #pragma unroll
            for (int ct = 0; ct < 2; ++ct) {
                int head = 2 * cg2 + ct;
                #pragma unroll
                for (int r = 0; r < 16; ++r) {
                    int erow = 32 * rt + (r & 3) + 8 * (r >> 2) + 4 * h5;
                    sm.sSc[erow][head] = ps[ct][r] * inv;
                }
            }
        }
    }
    __syncthreads();
    if (t < TE) {   // softmax over 4 heads
        float s0 = sm.sSc[t][0], s1 = sm.sSc[t][1];
        float s2 = sm.sSc[t][2], s3 = sm.sSc[t][3];
        float m = fmaxf(fmaxf(s0, s1), fmaxf(s2, s3));
        float e0 = expf(s0 - m), e1 = expf(s1 - m);
        float e2 = expf(s2 - m), e3 = expf(s3 - m);
        float den = e0 + e1 + e2 + e3;
        sm.sAttn[t][0] = e0 / den; sm.sAttn[t][1] = e1 / den;
        sm.sAttn[t][2] = e2 / den; sm.sAttn[t][3] = e3 / den;
    }
    __syncthreads();

    // ---- V GEMM + attend + residual (in-place on sHid) ----
    f32x16 vacc[2];
    vacc[0] = (f32x16)(0.0f); vacc[1] = (f32x16)(0.0f);
    gemm128(sm, WTv, vacc, t, rt, cg2, c, h5);
    {
        #pragma unroll
        for (int ct = 0; ct < 2; ++ct) {
            int col  = 64 * cg2 + 32 * ct + c;
            int head = 2 * cg2 + ct;
            float bv = sm.sBias[2 * HID + col];
            #pragma unroll
            for (int r = 0; r < 16; ++r) {
                int erow = 32 * rt + (r & 3) + 8 * (r >> 2) + 4 * h5;
                float at = sm.sAttn[erow][head];
                float hv = bf16_to_f32(sm.sHid[erow][col]);
                sm.sHid[erow][col] = f32_to_bf16(at * (vacc[ct][r] + bv) + hv);
            }
        }
    }
    // (first barrier inside the next gemm128 covers the in-place hazard)

    // ---- GEMM3 + final dot with W_o2 ----
    f32x16 oacc[2];
    oacc[0] = (f32x16)(0.0f); oacc[1] = (f32x16)(0.0f);
    gemm128(sm, WTo1, oacc, t, rt, cg2, c, h5);
    {
        float pr[16];
        #pragma unroll
        for (int r = 0; r < 16; ++r) pr[r] = 0.f;
        #pragma unroll
        for (int ct = 0; ct < 2; ++ct) {
            int col = 64 * cg2 + 32 * ct + c;
            float bo = sm.sBias[3 * HID + col];
            float wo = sm.sBias[4 * HID + col];
            #pragma unroll
            for (int r = 0; r < 16; ++r)
                pr[r] += fmaxf(oacc[ct][r] + bo, 0.f) * wo;
        }
        #pragma unroll
        for (int m = 1; m < 32; m <<= 1)
            #pragma unroll
            for (int r = 0; r < 16; ++r)
                pr[r] += __shfl_xor(pr[r], m, 64);
        if (c == 0) {
            #pragma unroll
            for (int r = 0; r < 16; ++r) {
                int erow = 32 * rt + (r & 3) + 8 * (r >> 2) + 4 * h5;
                sm.sPart[erow][cg2] = pr[r];
            }
        }
    }
    __syncthreads();
    if (t < TE) {
        int ge = bs + t;
        if (ge < E) {
            float val = sm.sPart[t][0] + sm.sPart[t][1] + ldx<F32>(b_o2, 0);
            // F32 path writes fp32 (round-10 lesson: output buffer is fp32).
            if (F32) ((float*)outp)[ge] = val;
            else     ((unsigned short*)outp)[ge] = f32_to_bf16(val);
        }
    }
}

__global__ __launch_bounds__(256, 4) void RelationAttentionMLPHead_10539849744626_kernel(
    const void* nodeEmb, const unsigned short* nodeBf16, int useConv,
    const int* edgeIdx, const int* relType,
    const unsigned short* WTe, const unsigned short* WTk,
    const unsigned short* WTv, const unsigned short* WTo1,
    const void* b_edge, const void* b_k, const void* b_v,
    const void* b_o1, const void* W_o2, const void* b_o2,
    const float* Qtab, void* outp, int E)
{
    __shared__ Smem sm;     // single allocation shared by all instantiations
    if (detect_f32(nodeEmb)) {
        if (useConv)
            fused_body<true, true >(sm, nodeBf16, edgeIdx, relType, WTe, WTk, WTv, WTo1,
                                    b_edge, b_k, b_v, b_o1, W_o2, b_o2, Qtab, outp, E);
        else
            fused_body<true, false>(sm, nodeEmb, edgeIdx, relType, WTe, WTk, WTv, WTo1,
                                    b_edge, b_k, b_v, b_o1, W_o2, b_o2, Qtab, outp, E);
    } else {
        fused_body<false, true>(sm, nodeEmb, edgeIdx, relType, WTe, WTk, WTv, WTo1,
                                b_edge, b_k, b_v, b_o1, W_o2, b_o2, Qtab, outp, E);
    }
}

extern "C" void kernel_launch(void* const* d_in, const int* in_sizes, int n_in,
                              void* d_out, int out_size, void* d_ws, size_t ws_size,
                              hipStream_t stream) {
    (void)n_in;

    const void* nodeEmb = d_in[0];
    const int*  edgeIdx = (const int*)d_in[1];
    const int*  relType = (const int*)d_in[2];
    const void* rel_emb = d_in[3];
    const void* W_edge  = d_in[4];
    const void* b_edge  = d_in[5];
    const void* W_q     = d_in[6];
    const void* b_q     = d_in[7];
    const void* W_k     = d_in[8];
    const void* b_k     = d_in[9];
    const void* W_v     = d_in[10];
    const void* b_v     = d_in[11];
    const void* W_o1    = d_in[12];
    const void* b_o1    = d_in[13];
    const void* W_o2    = d_in[14];
    const void* b_o2    = d_in[15];

    int E = out_size;
    if (E <= 0) E = in_sizes ? in_sizes[2] : 0;
    if (E <= 0) E = 500000;

    unsigned long long nodeElems =
        (in_sizes && in_sizes[0] > 0) ? (unsigned long long)in_sizes[0] : 25600000ull;

    // d_ws layout (recomputed every launch; graph-safe)
    char* ws = (char*)d_ws;
    float*          Qtab     = (float*)ws;                      // 5120 B
    unsigned short* WTe      = (unsigned short*)(ws + 8192);    // 131072 B
    unsigned short* WTk      = (unsigned short*)(ws + 139264);  // 32768 B
    unsigned short* WTv      = (unsigned short*)(ws + 172032);  // 32768 B
    unsigned short* WTo1     = (unsigned short*)(ws + 204800);  // 32768 B
    unsigned short* nodeBf16 = (unsigned short*)(ws + 237568);  // nodeElems*2 B

    size_t need = 237568ull + nodeElems * 2ull;
    int useConv = (ws_size >= need) ? 1 : 0;
    int convBlocks = useConv ? (int)((nodeElems + 2047ull) / 2048ull) : 0;

    prep_kernel<<<convBlocks + 449, 256, 0, stream>>>(
        nodeEmb, W_edge, W_k, W_v, W_o1, rel_emb, W_q, b_q,
        WTe, WTk, WTv, WTo1, Qtab, nodeBf16, convBlocks, nodeElems);

    int grid = (E + TE - 1) / TE;
    if (grid < 1) grid = 1;

    RelationAttentionMLPHead_10539849744626_kernel<<<grid, 256, 0, stream>>>(
        nodeEmb, nodeBf16, useConv, edgeIdx, relType, WTe, WTk, WTv, WTo1,
        b_edge, b_k, b_v, b_o1, W_o2, b_o2, Qtab, d_out, E);
}